// Round 1
// baseline (428.186 us; speedup 1.0000x reference)
//
#include <hip/hip_runtime.h>
#include <stdint.h>

#define NB 32
#define NS 8192
#define ND 128
#define KTOP 4096
#define NCLUST 1024
#define CIN 512
#define HIDN 256
#define NMEM 128
#define NCLS 10
#define HALFCNT 4194304u   // (NB*NCLUST*HIDN)/2

// ---------------- threefry2x32-20, JAX-exact, key = (0, 1234) ----------------
__device__ __forceinline__ unsigned int rotl32(unsigned int v, int r) {
  return (v << r) | (v >> (32 - r));
}

__device__ __forceinline__ void threefry_block(unsigned int& x0, unsigned int& x1) {
  const unsigned int k0 = 0u;
  const unsigned int k1 = 1234u;
  const unsigned int k2 = 0x1BD11BDAu ^ 0u ^ 1234u;
  x0 += k0; x1 += k1;
#define TF_R(r) { x0 += x1; x1 = rotl32(x1, (r)); x1 ^= x0; }
  TF_R(13) TF_R(15) TF_R(26) TF_R(6)   x0 += k1; x1 += k2 + 1u;
  TF_R(17) TF_R(29) TF_R(16) TF_R(24)  x0 += k2; x1 += k0 + 2u;
  TF_R(13) TF_R(15) TF_R(26) TF_R(6)   x0 += k0; x1 += k1 + 3u;
  TF_R(17) TF_R(29) TF_R(16) TF_R(24)  x0 += k1; x1 += k2 + 4u;
  TF_R(13) TF_R(15) TF_R(26) TF_R(6)   x0 += k2; x1 += k0 + 5u;
#undef TF_R
}

// keep = (uniform(flat) < 0.5) == top bit of threefry word is 0
__device__ __forceinline__ bool mask_keep(unsigned int flat, bool lowhalf) {
  unsigned int a, b;
  if (lowhalf) { a = flat;           b = flat + HALFCNT; }
  else         { a = flat - HALFCNT; b = flat; }
  threefry_block(a, b);
  const unsigned int w = lowhalf ? a : b;
  return (w & 0x80000000u) == 0u;
}

// ---------------- kernel 1: token norms -> sort keys; zero xc ----------------
__global__ __launch_bounds__(256) void norms_kernel(
    const float* __restrict__ x, unsigned long long* __restrict__ keys,
    float* __restrict__ xc) {
  const int t = blockIdx.x * 256 + threadIdx.x;
  if (t < NB * HIDN) xc[t] = 0.0f;          // zero the pooled-sum accumulator
  const int token = t >> 5;                 // 32 lanes per token
  const int l = t & 31;
  const float4 v = ((const float4*)(x + (size_t)token * ND))[l];
  float ss = v.x * v.x + v.y * v.y + v.z * v.z + v.w * v.w;
#pragma unroll
  for (int off = 16; off >= 1; off >>= 1) ss += __shfl_xor(ss, off);
  if (l == 0) {
    const float nrm = sqrtf(ss);
    const unsigned int ub = ~__float_as_uint(nrm);  // norms >= 0: bits monotonic
    keys[token] = ((unsigned long long)ub << 32) | (unsigned int)(token & (NS - 1));
  }
}

// ---------------- kernel 2: per-batch bitonic sort (ascending composite key) --
__global__ __launch_bounds__(1024) void sort_kernel(
    const unsigned long long* __restrict__ keys, unsigned int* __restrict__ topk) {
  __shared__ unsigned long long k_lds[NS];  // 64 KiB
  const int b = blockIdx.x;
  const int tid = threadIdx.x;
#pragma unroll
  for (int t = 0; t < NS / 1024; ++t)
    k_lds[tid + t * 1024] = keys[(size_t)b * NS + tid + t * 1024];
  for (int k = 2; k <= NS; k <<= 1) {
    for (int j = k >> 1; j > 0; j >>= 1) {
      __syncthreads();
#pragma unroll
      for (int t = 0; t < NS / 1024; ++t) {
        const int i = tid + t * 1024;
        const int ixj = i ^ j;
        if (ixj > i) {
          const unsigned long long a = k_lds[i];
          const unsigned long long c = k_lds[ixj];
          const bool up = (i & k) == 0;
          if ((a > c) == up) { k_lds[i] = c; k_lds[ixj] = a; }
        }
      }
    }
  }
  __syncthreads();
#pragma unroll
  for (int t = 0; t < KTOP / 1024; ++t) {
    const int j = tid + t * 1024;
    topk[b * KTOP + j] = (unsigned int)k_lds[j];   // low 32 bits = token idx
  }
}

// ---------------- kernel 3: gather + f32 GEMM + bias + mask + relu + col-sum --
#define MT 64
#define NT 128
#define KT 64

__global__ __launch_bounds__(256) void gemm_kernel(
    const float* __restrict__ x, const float* __restrict__ Wfc,
    const float* __restrict__ bfc, const unsigned int* __restrict__ topk,
    float* __restrict__ xc) {
  __shared__ float A_lds[KT][MT];   // 16 KiB, k-major (broadcast reads)
  __shared__ float B_lds[KT][NT];   // 32 KiB
  __shared__ int   tok[MT * 4];     // token idx per (cluster, slot)
  __shared__ float red[4][NT];

  const int m0 = blockIdx.x * MT;   // cluster tile
  const int n0 = blockIdx.y * NT;   // hid tile
  const int b  = blockIdx.z;
  const int t  = threadIdx.x;
  const int ty = t >> 5;            // 0..7  -> 8 rows each
  const int tx = t & 31;            // 0..31 -> 4 cols each

  tok[t] = (int)topk[b * KTOP + m0 * 4 + t];   // 256 entries

  float acc[8][4] = {};

  for (int kt = 0; kt < CIN / KT; ++kt) {
    __syncthreads();   // prev compute done (and tok ready on first iter)
    // --- stage A: 64 rows x 64 k  (row = t>>2, seg = t&3 -> 16 floats) ---
    {
      const int r = t >> 2, seg = t & 3;
      const int slot = kt >> 1, d0 = (kt & 1) * 64;
      const int token = tok[r * 4 + slot];
      const float4* src =
          (const float4*)(x + ((size_t)(b * NS + token)) * ND + d0 + seg * 16);
      float vals[16];
      *(float4*)&vals[0]  = src[0];
      *(float4*)&vals[4]  = src[1];
      *(float4*)&vals[8]  = src[2];
      *(float4*)&vals[12] = src[3];
#pragma unroll
      for (int j = 0; j < 16; ++j) A_lds[seg * 16 + j][r] = vals[j];
    }
    // --- stage B: W_fc[n0+n][kt*64 + k] -> B_lds[k][n] ---
    {
      const int n = t >> 1, half = t & 1;
      const float* wsrc = Wfc + (size_t)(n0 + n) * CIN + kt * KT + half * 32;
      float wv[32];
#pragma unroll
      for (int q = 0; q < 8; ++q) *(float4*)&wv[q * 4] = ((const float4*)wsrc)[q];
#pragma unroll
      for (int j = 0; j < 32; ++j) B_lds[half * 32 + j][n] = wv[j];
    }
    __syncthreads();
    // --- inner: 64 k-steps, 8x4 micro-tile ---
#pragma unroll 8
    for (int kk = 0; kk < KT; ++kk) {
      const float4 a0 = *(const float4*)&A_lds[kk][ty * 8];
      const float4 a1 = *(const float4*)&A_lds[kk][ty * 8 + 4];
      const float4 bb = *(const float4*)&B_lds[kk][tx * 4];
      const float av[8] = {a0.x, a0.y, a0.z, a0.w, a1.x, a1.y, a1.z, a1.w};
      const float bv[4] = {bb.x, bb.y, bb.z, bb.w};
#pragma unroll
      for (int i = 0; i < 8; ++i)
#pragma unroll
        for (int jj = 0; jj < 4; ++jj)
          acc[i][jj] = fmaf(av[i], bv[jj], acc[i][jj]);
    }
  }

  // --- epilogue: bias, deterministic bernoulli mask, relu, column partials ---
  const int colbase = n0 + tx * 4;
  const float bias[4] = {bfc[colbase], bfc[colbase + 1], bfc[colbase + 2],
                         bfc[colbase + 3]};
  const bool lowhalf = (b < NB / 2);
  const unsigned int rowflatbase =
      (unsigned int)(b * NCLUST + m0 + ty * 8) * HIDN + (unsigned int)colbase;
  float csum[4] = {0.f, 0.f, 0.f, 0.f};
#pragma unroll
  for (int i = 0; i < 8; ++i) {
    const unsigned int flat0 = rowflatbase + (unsigned int)i * HIDN;
#pragma unroll
    for (int jj = 0; jj < 4; ++jj) {
      const bool keep = mask_keep(flat0 + jj, lowhalf);
      float v = acc[i][jj] + bias[jj];
      v = keep ? fmaxf(v, 0.0f) : 0.0f;
      csum[jj] += v;
    }
  }
  // fold the two ty's of each wave, then cross-wave via LDS
#pragma unroll
  for (int jj = 0; jj < 4; ++jj) csum[jj] += __shfl_xor(csum[jj], 32);
  const int w = t >> 6;
  if ((t & 63) < 32) {
#pragma unroll
    for (int jj = 0; jj < 4; ++jj) red[w][tx * 4 + jj] = csum[jj];
  }
  __syncthreads();
  if (t < NT) {
    const float s2 = red[0][t] + red[1][t] + red[2][t] + red[3][t];
    atomicAdd(&xc[b * HIDN + n0 + t], s2);
  }
}

// ---------------- kernel 4: mean + memory MLP + output head ----------------
__global__ __launch_bounds__(128) void tail_kernel(
    const float* __restrict__ xc, const float* __restrict__ memory,
    const float* __restrict__ Wmem, const float* __restrict__ bmem,
    const float* __restrict__ Wout, const float* __restrict__ bout,
    float* __restrict__ out) {
  __shared__ __align__(16) float xl[HIDN];
  __shared__ float ul[NMEM];
  const int b = blockIdx.x, t = threadIdx.x;
  xl[t]       = xc[b * HIDN + t] * (1.0f / NCLUST);
  xl[t + 128] = xc[b * HIDN + t + 128] * (1.0f / NCLUST);
  __syncthreads();
  float a = 0.0f;
  const float4* wr = (const float4*)(Wmem + (size_t)t * HIDN);
#pragma unroll 4
  for (int q = 0; q < HIDN / 4; ++q) {
    const float4 wv = wr[q];
    const float4 xv = *(const float4*)&xl[q * 4];
    a = fmaf(wv.x, xv.x, a); a = fmaf(wv.y, xv.y, a);
    a = fmaf(wv.z, xv.z, a); a = fmaf(wv.w, xv.w, a);
  }
  a += bmem[t] + memory[b * NMEM + t];
  a = fmaxf(a, 0.0f);
  ul[t] = a;
  out[NB * NCLS + b * NMEM + t] = a;   // updated_memory after the 320 outputs
  __syncthreads();
  if (t < NCLS) {
    float o = 0.0f;
#pragma unroll 4
    for (int m = 0; m < NMEM; ++m) o = fmaf(ul[m], Wout[t * NMEM + m], o);
    out[b * NCLS + t] = o + bout[t];
  }
}

// ---------------- launcher ----------------
extern "C" void kernel_launch(void* const* d_in, const int* in_sizes, int n_in,
                              void* d_out, int out_size, void* d_ws, size_t ws_size,
                              hipStream_t stream) {
  (void)in_sizes; (void)n_in; (void)out_size; (void)ws_size;
  const float* x    = (const float*)d_in[0];
  const float* mem  = (const float*)d_in[1];
  const float* Wfc  = (const float*)d_in[2];
  const float* bfc  = (const float*)d_in[3];
  const float* Wmem = (const float*)d_in[4];
  const float* bmem = (const float*)d_in[5];
  const float* Wout = (const float*)d_in[6];
  const float* bout = (const float*)d_in[7];
  float* out = (float*)d_out;

  unsigned long long* keys = (unsigned long long*)d_ws;                  // 2 MiB
  unsigned int* topk = (unsigned int*)((char*)d_ws + (size_t)NB * NS * 8);  // 512 KiB
  float* xc = (float*)((char*)d_ws + (size_t)NB * NS * 8 + (size_t)NB * KTOP * 4);

  norms_kernel<<<dim3(NB * NS / 8), 256, 0, stream>>>(x, keys, xc);
  sort_kernel<<<dim3(NB), 1024, 0, stream>>>(keys, topk);
  gemm_kernel<<<dim3(NCLUST / MT, HIDN / NT, NB), 256, 0, stream>>>(x, Wfc, bfc,
                                                                    topk, xc);
  tail_kernel<<<dim3(NB), 128, 0, stream>>>(xc, mem, Wmem, bmem, Wout, bout, out);
}

// Round 2
// 305.480 us; speedup vs baseline: 1.4017x; 1.4017x over previous
//
#include <hip/hip_runtime.h>
#include <stdint.h>

#define NB 32
#define NS 8192
#define ND 128
#define KTOP 4096
#define NCLUST 1024
#define CIN 512
#define HIDN 256
#define NMEM 128
#define NCLS 10
#define HALFCNT 4194304u   // (NB*NCLUST*HIDN)/2

typedef unsigned long long ull;
typedef __attribute__((ext_vector_type(8))) short bf16x8;
typedef __attribute__((ext_vector_type(4))) float f32x4;

// ---------------- threefry2x32-20, JAX-exact, key = (0, 1234) ----------------
__device__ __forceinline__ unsigned int rotl32(unsigned int v, int r) {
  return (v << r) | (v >> (32 - r));
}

__device__ __forceinline__ void threefry_block(unsigned int& x0, unsigned int& x1) {
  const unsigned int k0 = 0u;
  const unsigned int k1 = 1234u;
  const unsigned int k2 = 0x1BD11BDAu ^ 0u ^ 1234u;
  x0 += k0; x1 += k1;
#define TF_R(r) { x0 += x1; x1 = rotl32(x1, (r)); x1 ^= x0; }
  TF_R(13) TF_R(15) TF_R(26) TF_R(6)   x0 += k1; x1 += k2 + 1u;
  TF_R(17) TF_R(29) TF_R(16) TF_R(24)  x0 += k2; x1 += k0 + 2u;
  TF_R(13) TF_R(15) TF_R(26) TF_R(6)   x0 += k0; x1 += k1 + 3u;
  TF_R(17) TF_R(29) TF_R(16) TF_R(24)  x0 += k1; x1 += k2 + 4u;
  TF_R(13) TF_R(15) TF_R(26) TF_R(6)   x0 += k2; x1 += k0 + 5u;
#undef TF_R
}

__device__ __forceinline__ bool mask_keep(unsigned int flat) {
  const bool low = flat < HALFCNT;
  unsigned int a, b;
  if (low) { a = flat;           b = flat + HALFCNT; }
  else     { a = flat - HALFCNT; b = flat; }
  threefry_block(a, b);
  const unsigned int w = low ? a : b;
  return (w & 0x80000000u) == 0u;
}

__device__ __forceinline__ unsigned int f2bf(float f) {
  unsigned int u = __float_as_uint(f);
  return (u + 0x7fffu + ((u >> 16) & 1u)) >> 16;
}
__device__ __forceinline__ unsigned int pack2bf(float lo, float hi) {
  return f2bf(lo) | (f2bf(hi) << 16);
}

__device__ __forceinline__ void gload_lds16(const void* g, void* l) {
  __builtin_amdgcn_global_load_lds(
      (const __attribute__((address_space(1))) unsigned int*)g,
      (__attribute__((address_space(3))) unsigned int*)l, 16, 0, 0);
}

__device__ __forceinline__ ull shfl_xor_u64(ull x, int m) {
  unsigned int lo = (unsigned int)x, hi = (unsigned int)(x >> 32);
  lo = (unsigned int)__shfl_xor((int)lo, m);
  hi = (unsigned int)__shfl_xor((int)hi, m);
  return ((ull)hi << 32) | lo;
}

// ---------------- kernel 0: W_fc f32 -> bf16 (same [256][512] layout) -------
__global__ __launch_bounds__(256) void wprep_kernel(
    const float* __restrict__ Wfc, unsigned short* __restrict__ Wbf) {
  const int t = blockIdx.x * 256 + threadIdx.x;     // 16384 threads * 8 elems
  const float4* s = (const float4*)(Wfc + (size_t)t * 8);
  const float4 a = s[0], b = s[1];
  uint4 o;
  o.x = pack2bf(a.x, a.y); o.y = pack2bf(a.z, a.w);
  o.z = pack2bf(b.x, b.y); o.w = pack2bf(b.z, b.w);
  *(uint4*)(Wbf + (size_t)t * 8) = o;
}

// ---------------- kernel 1: token norms -> sort keys; zero xc ----------------
__global__ __launch_bounds__(256) void norms_kernel(
    const float* __restrict__ x, ull* __restrict__ keys,
    float* __restrict__ xc) {
  const int t = blockIdx.x * 256 + threadIdx.x;
  if (t < NB * HIDN) xc[t] = 0.0f;
  const int token = t >> 5;
  const int l = t & 31;
  const float4 v = ((const float4*)(x + (size_t)token * ND))[l];
  float ss = v.x * v.x + v.y * v.y + v.z * v.z + v.w * v.w;
#pragma unroll
  for (int off = 16; off >= 1; off >>= 1) ss += __shfl_xor(ss, off);
  if (l == 0) {
    const float nrm = sqrtf(ss);
    const unsigned int ub = ~__float_as_uint(nrm);
    keys[token] = ((ull)ub << 32) | (unsigned int)(token & (NS - 1));
  }
}

// ------- kernel 2: per-batch hybrid bitonic sort (reg / shfl / LDS) ---------
#define CMPEX(J)                                                        \
  {                                                                     \
    _Pragma("unroll") for (int r = 0; r < 8; ++r) {                     \
      if ((r & (J)) == 0) {                                             \
        const int i0 = (tid << 3) + r;                                  \
        const bool up2 = ((i0 & k) == 0);                               \
        const ull lo = v[r], hi = v[r | (J)];                           \
        const ull mn = lo < hi ? lo : hi;                               \
        const ull mx = lo < hi ? hi : lo;                               \
        v[r] = up2 ? mn : mx;                                           \
        v[r | (J)] = up2 ? mx : mn;                                     \
      }                                                                 \
    }                                                                   \
  }

__global__ __launch_bounds__(1024) void sort_kernel(
    const ull* __restrict__ keys, unsigned int* __restrict__ topk) {
  __shared__ ull slds[NS];               // transposed layout: [r][tid]
  const int b = blockIdx.x;
  const int tid = threadIdx.x;
  ull v[8];
  const ull* src = keys + (size_t)b * NS + tid * 8;
#pragma unroll
  for (int r = 0; r < 8; ++r) v[r] = src[r];

  for (int k = 2; k <= NS; k <<= 1) {
    // cross-wave rounds via LDS (j = 512..4096)
    for (int j = k >> 1; j >= 512; j >>= 1) {
      __syncthreads();                   // protect prev round's reads (WAR)
#pragma unroll
      for (int r = 0; r < 8; ++r) slds[r * 1024 + tid] = v[r];
      __syncthreads();
      const int ptid = tid ^ (j >> 3);
      const bool up2 = (((tid << 3) & k) == 0);
      const bool lower = (((tid << 3) & j) == 0);
      const bool keepmin = (up2 == lower);
#pragma unroll
      for (int r = 0; r < 8; ++r) {
        const ull p = slds[r * 1024 + ptid];
        const ull mn = v[r] < p ? v[r] : p;
        const ull mx = v[r] < p ? p : v[r];
        v[r] = keepmin ? mn : mx;
      }
    }
    // intra-wave rounds via shfl (j = 8..256)
    {
      int jstart = (k >> 1) < 256 ? (k >> 1) : 256;
      for (int j = jstart; j >= 8; j >>= 1) {
        const int lanemask = j >> 3;
        const bool up2 = (((tid << 3) & k) == 0);
        const bool lower = (((tid << 3) & j) == 0);
        const bool keepmin = (up2 == lower);
#pragma unroll
        for (int r = 0; r < 8; ++r) {
          const ull p = shfl_xor_u64(v[r], lanemask);
          const ull mn = v[r] < p ? v[r] : p;
          const ull mx = v[r] < p ? p : v[r];
          v[r] = keepmin ? mn : mx;
        }
      }
    }
    // in-register rounds (j = 4,2,1)
    if (k >= 8)      { CMPEX(4) CMPEX(2) CMPEX(1) }
    else if (k == 4) { CMPEX(2) CMPEX(1) }
    else             { CMPEX(1) }
  }

  if (tid < KTOP / 8) {
#pragma unroll
    for (int r = 0; r < 8; ++r)
      topk[b * KTOP + tid * 8 + r] = (unsigned int)v[r];
  }
}

// ------ kernel 3: gather + bf16 MFMA GEMM + bias + mask + relu + col-sum ----
// C tile 128x128, BK=64. 4 waves, each wave 64x64 (4x4 frags of 16x16x32).
__global__ __launch_bounds__(256) void gemm_kernel(
    const float* __restrict__ x, const unsigned short* __restrict__ Wbf,
    const float* __restrict__ bfc, const unsigned int* __restrict__ topk,
    float* __restrict__ xc) {
  __shared__ __align__(16) unsigned short Al[128 * 64];  // 16 KiB, swizzled
  __shared__ __align__(16) unsigned short Bl[128 * 64];  // 16 KiB, swizzled
  __shared__ int tokL[512];
  __shared__ float red[4][64];

  const int bid = blockIdx.x;            // 256 m-tiles
  const int m0 = bid * 128;
  const int bb = bid >> 3;               // batch (1024 clusters / 128 per tile)
  const int n0 = blockIdx.y * 128;
  const int t = threadIdx.x;
  const int w = t >> 6, l = t & 63;
  const int wr = w >> 1, wc = w & 1;
  const int lrow = l & 15, lk = l >> 4;

  // token table for this tile's 128 clusters
  {
    const int base = bb * KTOP + (bid & 7) * 512;
    tokL[t] = (int)topk[base + t];
    tokL[t + 256] = (int)topk[base + t + 256];
  }
  __syncthreads();

  f32x4 acc[4][4];
#pragma unroll
  for (int m = 0; m < 4; ++m)
#pragma unroll
    for (int n = 0; n < 4; ++n) acc[m][n] = (f32x4)0.f;

  // --- A-stage thread mapping: row = t>>1 (cluster-in-tile), kh = t&1 ---
  const int arow = t >> 1, kh = t & 1;
  float4 ar[8];
  // preload chunk 0
  {
    const int token = tokL[arow * 4 + 0];
    const float* asrc = x + ((size_t)bb * NS + token) * ND + kh * 32;
#pragma unroll
    for (int q = 0; q < 8; ++q) ar[q] = ((const float4*)asrc)[q];
  }

  // per-lane source swizzle for B staging (linear LDS dest, swizzled source)
  const int brow_in8 = l >> 3;                       // row within 8-row group
  const int bkb_src = ((l & 7) * 16) ^ (brow_in8 << 4);

  for (int kt = 0; kt < 8; ++kt) {
    // write A regs (chunk kt) to swizzled LDS
    {
      const int kb0 = kh * 64;
#pragma unroll
      for (int c = 0; c < 4; ++c) {
        const float4 lo = ar[c * 2], hi = ar[c * 2 + 1];
        uint4 pw;
        pw.x = pack2bf(lo.x, lo.y); pw.y = pack2bf(lo.z, lo.w);
        pw.z = pack2bf(hi.x, hi.y); pw.w = pack2bf(hi.z, hi.w);
        const int kb = kb0 + c * 16;
        const int off = arow * 128 + (kb ^ ((arow & 7) << 4));
        *(uint4*)((char*)Al + off) = pw;
      }
    }
    // stage B (bf16) via global_load_lds, pre-swizzled source
    {
#pragma unroll
      for (int q = 0; q < 4; ++q) {
        const int grp = w * 4 + q;
        const int row = grp * 8 + brow_in8;
        const char* g = (const char*)Wbf + (size_t)(n0 + row) * 1024 +
                        kt * 128 + bkb_src;
        gload_lds16(g, (char*)Bl + grp * 1024);
      }
    }
    __syncthreads();   // drains vmcnt+lgkm: A and B tiles ready

    // prefetch A regs for chunk kt+1 (flies under the MFMA phase)
    if (kt < 7) {
      const int c = kt + 1;
      const int token = tokL[arow * 4 + (c >> 1)];
      const float* asrc =
          x + ((size_t)bb * NS + token) * ND + (c & 1) * 64 + kh * 32;
#pragma unroll
      for (int q = 0; q < 8; ++q) ar[q] = ((const float4*)asrc)[q];
    }

    // compute: 2 kk-steps x 16 MFMA
    const int swz = (lrow & 7) << 4;
#pragma unroll
    for (int kk = 0; kk < 2; ++kk) {
      const int koff = (kk * 64 + lk * 16) ^ swz;
      bf16x8 af[4], bfr[4];
#pragma unroll
      for (int m = 0; m < 4; ++m)
        af[m] = *(const bf16x8*)((const char*)Al +
                                 (wr * 64 + m * 16 + lrow) * 128 + koff);
#pragma unroll
      for (int n = 0; n < 4; ++n)
        bfr[n] = *(const bf16x8*)((const char*)Bl +
                                  (wc * 64 + n * 16 + lrow) * 128 + koff);
#pragma unroll
      for (int m = 0; m < 4; ++m)
#pragma unroll
        for (int n = 0; n < 4; ++n)
          acc[m][n] = __builtin_amdgcn_mfma_f32_16x16x32_bf16(
              af[m], bfr[n], acc[m][n], 0, 0, 0);
    }
    __syncthreads();   // LDS consumed; safe to overwrite next iter
  }

  // --- epilogue: bias + deterministic bernoulli + relu + column partials ---
  float bias_n[4];
#pragma unroll
  for (int n = 0; n < 4; ++n) bias_n[n] = bfc[n0 + wc * 64 + n * 16 + lrow];

  const int rowbase = m0 + wr * 64 + lk * 4;
  float csum[4] = {0.f, 0.f, 0.f, 0.f};
#pragma unroll
  for (int n = 0; n < 4; ++n) {
    const unsigned int gcol = (unsigned int)(n0 + wc * 64 + n * 16 + lrow);
#pragma unroll
    for (int m = 0; m < 4; ++m) {
#pragma unroll
      for (int reg = 0; reg < 4; ++reg) {
        const unsigned int gm = (unsigned int)(rowbase + m * 16 + reg);
        const unsigned int flat = gm * 256u + gcol;
        const bool keep = mask_keep(flat);
        float vv = acc[m][n][reg] + bias_n[n];
        vv = keep ? fmaxf(vv, 0.0f) : 0.0f;
        csum[n] += vv;
      }
    }
  }
  // reduce across lk groups (rows) within wave
#pragma unroll
  for (int n = 0; n < 4; ++n) {
    csum[n] += __shfl_xor(csum[n], 16);
    csum[n] += __shfl_xor(csum[n], 32);
  }
  if (l < 16) {
#pragma unroll
    for (int n = 0; n < 4; ++n) red[w][n * 16 + l] = csum[n];
  }
  __syncthreads();
  if (t < 128) {
    const int cwc = t >> 6, c = t & 63;
    const float s = red[cwc][c] + red[cwc + 2][c];
    atomicAdd(&xc[bb * HIDN + n0 + t], s);
  }
}

// ---------------- kernel 4: mean + memory MLP + output head ----------------
__global__ __launch_bounds__(128) void tail_kernel(
    const float* __restrict__ xc, const float* __restrict__ memory,
    const float* __restrict__ Wmem, const float* __restrict__ bmem,
    const float* __restrict__ Wout, const float* __restrict__ bout,
    float* __restrict__ out) {
  __shared__ __align__(16) float xl[HIDN];
  __shared__ float ul[NMEM];
  const int b = blockIdx.x, t = threadIdx.x;
  xl[t]       = xc[b * HIDN + t] * (1.0f / NCLUST);
  xl[t + 128] = xc[b * HIDN + t + 128] * (1.0f / NCLUST);
  __syncthreads();
  float a = 0.0f;
  const float4* wr2 = (const float4*)(Wmem + (size_t)t * HIDN);
#pragma unroll 4
  for (int q = 0; q < HIDN / 4; ++q) {
    const float4 wv = wr2[q];
    const float4 xv = *(const float4*)&xl[q * 4];
    a = fmaf(wv.x, xv.x, a); a = fmaf(wv.y, xv.y, a);
    a = fmaf(wv.z, xv.z, a); a = fmaf(wv.w, xv.w, a);
  }
  a += bmem[t] + memory[b * NMEM + t];
  a = fmaxf(a, 0.0f);
  ul[t] = a;
  out[NB * NCLS + b * NMEM + t] = a;
  __syncthreads();
  if (t < NCLS) {
    float o = 0.0f;
#pragma unroll 4
    for (int m = 0; m < NMEM; ++m) o = fmaf(ul[m], Wout[t * NMEM + m], o);
    out[b * NCLS + t] = o + bout[t];
  }
}

// ---------------- launcher ----------------
extern "C" void kernel_launch(void* const* d_in, const int* in_sizes, int n_in,
                              void* d_out, int out_size, void* d_ws, size_t ws_size,
                              hipStream_t stream) {
  (void)in_sizes; (void)n_in; (void)out_size; (void)ws_size;
  const float* x    = (const float*)d_in[0];
  const float* mem  = (const float*)d_in[1];
  const float* Wfc  = (const float*)d_in[2];
  const float* bfc  = (const float*)d_in[3];
  const float* Wmem = (const float*)d_in[4];
  const float* bmem = (const float*)d_in[5];
  const float* Wout = (const float*)d_in[6];
  const float* bout = (const float*)d_in[7];
  float* out = (float*)d_out;

  char* ws = (char*)d_ws;
  ull* keys = (ull*)ws;                                               // 2 MiB
  unsigned int* topk = (unsigned int*)(ws + (size_t)NB * NS * 8);     // 512 KiB
  float* xc = (float*)(ws + (size_t)NB * NS * 8 + (size_t)NB * KTOP * 4);
  unsigned short* Wbf = (unsigned short*)(ws + (size_t)NB * NS * 8 +
                                          (size_t)NB * KTOP * 4 +
                                          (size_t)NB * HIDN * 4);     // 256 KiB

  wprep_kernel<<<dim3(HIDN * CIN / (256 * 8)), 256, 0, stream>>>(Wfc, Wbf);
  norms_kernel<<<dim3(NB * NS / 8), 256, 0, stream>>>(x, keys, xc);
  sort_kernel<<<dim3(NB), 1024, 0, stream>>>(keys, topk);
  gemm_kernel<<<dim3(256, 2), 256, 0, stream>>>(x, Wbf, bfc, topk, xc);
  tail_kernel<<<dim3(NB), 128, 0, stream>>>(xc, mem, Wmem, bmem, Wout, bout, out);
}

// Round 4
// 277.021 us; speedup vs baseline: 1.5457x; 1.1027x over previous
//
#include <hip/hip_runtime.h>
#include <stdint.h>

#define NB 32
#define NS 8192
#define ND 128
#define KTOP 4096
#define NCLUST 1024
#define CIN 512
#define HIDN 256
#define NMEM 128
#define NCLS 10
#define HALFCNT 4194304u   // (NB*NCLUST*HIDN)/2

typedef unsigned long long ull;
typedef __attribute__((ext_vector_type(8))) short bf16x8;
typedef __attribute__((ext_vector_type(4))) float f32x4;

// ---------------- threefry2x32-20, JAX-exact, key = (0, 1234) ----------------
__device__ __forceinline__ unsigned int rotl32(unsigned int v, int r) {
  return (v << r) | (v >> (32 - r));
}

__device__ __forceinline__ void threefry_block(unsigned int& x0, unsigned int& x1) {
  const unsigned int k0 = 0u;
  const unsigned int k1 = 1234u;
  const unsigned int k2 = 0x1BD11BDAu ^ 0u ^ 1234u;
  x0 += k0; x1 += k1;
#define TF_R(r) { x0 += x1; x1 = rotl32(x1, (r)); x1 ^= x0; }
  TF_R(13) TF_R(15) TF_R(26) TF_R(6)   x0 += k1; x1 += k2 + 1u;
  TF_R(17) TF_R(29) TF_R(16) TF_R(24)  x0 += k2; x1 += k0 + 2u;
  TF_R(13) TF_R(15) TF_R(26) TF_R(6)   x0 += k0; x1 += k1 + 3u;
  TF_R(17) TF_R(29) TF_R(16) TF_R(24)  x0 += k1; x1 += k2 + 4u;
  TF_R(13) TF_R(15) TF_R(26) TF_R(6)   x0 += k2; x1 += k0 + 5u;
#undef TF_R
}

__device__ __forceinline__ bool mask_keep(unsigned int flat) {
  const bool low = flat < HALFCNT;
  unsigned int a, b;
  if (low) { a = flat;           b = flat + HALFCNT; }
  else     { a = flat - HALFCNT; b = flat; }
  threefry_block(a, b);
  const unsigned int w = low ? a : b;
  return (w & 0x80000000u) == 0u;
}

__device__ __forceinline__ unsigned int f2bf(float f) {
  unsigned int u = __float_as_uint(f);
  return (u + 0x7fffu + ((u >> 16) & 1u)) >> 16;
}
__device__ __forceinline__ unsigned int pack2bf(float lo, float hi) {
  return f2bf(lo) | (f2bf(hi) << 16);
}

__device__ __forceinline__ void gload_lds16(const void* g, void* l) {
  __builtin_amdgcn_global_load_lds(
      (const __attribute__((address_space(1))) unsigned int*)g,
      (__attribute__((address_space(3))) unsigned int*)l, 16, 0, 0);
}

__device__ __forceinline__ ull shfl_xor_u64(ull x, int m) {
  unsigned int lo = (unsigned int)x, hi = (unsigned int)(x >> 32);
  lo = (unsigned int)__shfl_xor((int)lo, m);
  hi = (unsigned int)__shfl_xor((int)hi, m);
  return ((ull)hi << 32) | lo;
}

// ------- kernel 1: token norms -> sort keys; zero xc; fused W_fc->bf16 ------
#define NORM_BLOCKS 32768
__global__ __launch_bounds__(256) void norms_kernel(
    const float* __restrict__ x, ull* __restrict__ keys,
    float* __restrict__ xc, const float* __restrict__ Wfc,
    unsigned short* __restrict__ Wbf) {
  const int blk = blockIdx.x;
  if (blk >= NORM_BLOCKS) {
    // W_fc f32 -> bf16, same [256][512] layout
    const int t = (blk - NORM_BLOCKS) * 256 + threadIdx.x;
    const float4* s = (const float4*)(Wfc + (size_t)t * 8);
    const float4 a = s[0], b = s[1];
    uint4 o;
    o.x = pack2bf(a.x, a.y); o.y = pack2bf(a.z, a.w);
    o.z = pack2bf(b.x, b.y); o.w = pack2bf(b.z, b.w);
    *(uint4*)(Wbf + (size_t)t * 8) = o;
    return;
  }
  const int t = blk * 256 + threadIdx.x;
  if (t < NB * HIDN) xc[t] = 0.0f;
  const int token = t >> 5;
  const int l = t & 31;
  const float4 v = ((const float4*)(x + (size_t)token * ND))[l];
  float ss = v.x * v.x + v.y * v.y + v.z * v.z + v.w * v.w;
#pragma unroll
  for (int off = 16; off >= 1; off >>= 1) ss += __shfl_xor(ss, off);
  if (l == 0) {
    const float nrm = sqrtf(ss);
    const unsigned int ub = ~__float_as_uint(nrm);
    keys[token] = ((ull)ub << 32) | (unsigned int)(token & (NS - 1));
  }
}

// ---- kernel 2a: per-half bitonic sort (4096 elems, asc for half 0, desc 1) --
#define CMPEX(J, K, HF)                                                 \
  {                                                                     \
    _Pragma("unroll") for (int r = 0; r < 8; ++r) {                     \
      if ((r & (J)) == 0) {                                             \
        const int i0 = (tid << 3) + r;                                  \
        const bool up2 = (((i0 & (K)) == 0) != (HF));                   \
        const ull lo = v[r], hi = v[r | (J)];                           \
        const ull mn = lo < hi ? lo : hi;                               \
        const ull mx = lo < hi ? hi : lo;                               \
        v[r] = up2 ? mn : mx;                                           \
        v[r | (J)] = up2 ? mx : mn;                                     \
      }                                                                 \
    }                                                                   \
  }

__global__ __launch_bounds__(512) void sortA_kernel(ull* __restrict__ keys) {
  __shared__ ull slds[8 * 512];          // 32 KiB, transposed [r][tid]
  const int b = blockIdx.x >> 1;
  const int half = blockIdx.x & 1;
  const bool hf = (half != 0);
  const int tid = threadIdx.x;
  ull v[8];
  ull* base = keys + (size_t)b * NS + half * 4096;
#pragma unroll
  for (int r = 0; r < 8; ++r) v[r] = base[tid * 8 + r];

  for (int k = 2; k <= 4096; k <<= 1) {
    // cross-wave rounds via LDS (j = 512..2048)
    for (int j = k >> 1; j >= 512; j >>= 1) {
      __syncthreads();
#pragma unroll
      for (int r = 0; r < 8; ++r) slds[r * 512 + tid] = v[r];
      __syncthreads();
      const int ptid = tid ^ (j >> 3);
      const bool up2 = ((((tid << 3) & k) == 0) != hf);
      const bool lower = (((tid << 3) & j) == 0);
      const bool keepmin = (up2 == lower);
#pragma unroll
      for (int r = 0; r < 8; ++r) {
        const ull p = slds[r * 512 + ptid];
        const ull mn = v[r] < p ? v[r] : p;
        const ull mx = v[r] < p ? p : v[r];
        v[r] = keepmin ? mn : mx;
      }
    }
    // intra-wave rounds via shfl (j = 8..256)
    {
      const int jstart = (k >> 1) < 256 ? (k >> 1) : 256;
      for (int j = jstart; j >= 8; j >>= 1) {
        const int lanemask = j >> 3;
        const bool up2 = ((((tid << 3) & k) == 0) != hf);
        const bool lower = (((tid << 3) & j) == 0);
        const bool keepmin = (up2 == lower);
#pragma unroll
        for (int r = 0; r < 8; ++r) {
          const ull p = shfl_xor_u64(v[r], lanemask);
          const ull mn = v[r] < p ? v[r] : p;
          const ull mx = v[r] < p ? p : v[r];
          v[r] = keepmin ? mn : mx;
        }
      }
    }
    // in-register rounds (j = 4,2,1)
    if (k >= 8)      { CMPEX(4, k, hf) CMPEX(2, k, hf) CMPEX(1, k, hf) }
    else if (k == 4) { CMPEX(2, k, hf) CMPEX(1, k, hf) }
    else             { CMPEX(1, k, hf) }
  }

#pragma unroll
  for (int r = 0; r < 8; ++r) base[tid * 8 + r] = v[r];
}

// ---- kernel 2b: merge asc-half + desc-half, keep top 4096 (lower), sorted ---
__global__ __launch_bounds__(512) void sortB_kernel(
    const ull* __restrict__ keys, unsigned int* __restrict__ topk) {
  __shared__ ull slds[8 * 512];          // 32 KiB (lower half only)
  const int b = blockIdx.x;
  const int tid = threadIdx.x;
  ull v[8];
  const ull* base = keys + (size_t)b * NS;
#pragma unroll
  for (int r = 0; r < 8; ++r) v[r] = base[tid * 8 + r];
  // j = 4096 round: partner of i is i+4096 -> pure per-thread min
#pragma unroll
  for (int r = 0; r < 8; ++r) {
    const ull u = base[4096 + tid * 8 + r];
    v[r] = v[r] < u ? v[r] : u;
  }
  // bitonic-merge lower half: j = 2048,1024,512 via LDS
  for (int j = 2048; j >= 512; j >>= 1) {
    __syncthreads();
#pragma unroll
    for (int r = 0; r < 8; ++r) slds[r * 512 + tid] = v[r];
    __syncthreads();
    const int ptid = tid ^ (j >> 3);
    const bool keepmin = (((tid << 3) & j) == 0);
#pragma unroll
    for (int r = 0; r < 8; ++r) {
      const ull p = slds[r * 512 + ptid];
      const ull mn = v[r] < p ? v[r] : p;
      const ull mx = v[r] < p ? p : v[r];
      v[r] = keepmin ? mn : mx;
    }
  }
  // j = 256..8 via shfl
  for (int j = 256; j >= 8; j >>= 1) {
    const int lanemask = j >> 3;
    const bool keepmin = (((tid << 3) & j) == 0);
#pragma unroll
    for (int r = 0; r < 8; ++r) {
      const ull p = shfl_xor_u64(v[r], lanemask);
      const ull mn = v[r] < p ? v[r] : p;
      const ull mx = v[r] < p ? p : v[r];
      v[r] = keepmin ? mn : mx;
    }
  }
  // j = 4,2,1 in registers (ascending merge: up2 always true)
  CMPEX(4, 8192, false) CMPEX(2, 8192, false) CMPEX(1, 8192, false)
#pragma unroll
  for (int r = 0; r < 8; ++r)
    topk[b * KTOP + tid * 8 + r] = (unsigned int)v[r];
}

// ------ kernel 3: gather + bf16 MFMA GEMM + bias + mask + relu + col-sum ----
// C tile 128x256 (full N), BK=64. 8 waves (2m x 4n), each wave 64x64.
__global__ __launch_bounds__(512) void gemm_kernel(
    const float* __restrict__ x, const unsigned short* __restrict__ Wbf,
    const float* __restrict__ bfc, const unsigned int* __restrict__ topk,
    float* __restrict__ xc) {
  __shared__ __align__(16) unsigned short Al[128 * 64];  // 16 KiB, swizzled
  __shared__ __align__(16) unsigned short Bl[256 * 64];  // 32 KiB, swizzled
  __shared__ int tokL[512];
  __shared__ float red[8][64];

  const int bid = blockIdx.x;            // 256 tiles (8 m-tiles x 32 batches)
  const int bb = bid >> 3;               // batch
  const int m0 = (bid & 7) * 128;        // cluster base within batch
  const int t = threadIdx.x;
  const int w = t >> 6, l = t & 63;
  const int wr = w >> 2, wc = w & 3;     // wave grid 2 x 4
  const int lrow = l & 15, lk = l >> 4;

  tokL[t] = (int)topk[bb * KTOP + m0 * 4 + t];   // 512 entries
  __syncthreads();

  f32x4 acc[4][4];
#pragma unroll
  for (int m = 0; m < 4; ++m)
#pragma unroll
    for (int n = 0; n < 4; ++n) acc[m][n] = (f32x4)0.f;

  // --- A-stage mapping: row = t>>2 (cluster-in-tile), seg = t&3 (16 k-vals) --
  const int arow = t >> 2, aseg = t & 3;
  float4 ar[4];
  {
    const int cs = aseg;                 // kt=0: chunk index = aseg
    const int token = tokL[arow * 4 + (cs >> 3)];
    const float* asrc = x + ((size_t)bb * NS + token) * ND + ((cs * 16) & 127);
#pragma unroll
    for (int q = 0; q < 4; ++q) ar[q] = ((const float4*)asrc)[q];
  }

  // per-lane source swizzle for B staging (linear LDS dest, swizzled source)
  const int brow_in8 = l >> 3;
  const int bkb_src = ((l & 7) * 16) ^ (brow_in8 << 4);

  for (int kt = 0; kt < 8; ++kt) {
    // write A regs (chunk kt) to swizzled LDS: 2 x uint4 per thread
    {
      uint4 p0, p1;
      p0.x = pack2bf(ar[0].x, ar[0].y); p0.y = pack2bf(ar[0].z, ar[0].w);
      p0.z = pack2bf(ar[1].x, ar[1].y); p0.w = pack2bf(ar[1].z, ar[1].w);
      p1.x = pack2bf(ar[2].x, ar[2].y); p1.y = pack2bf(ar[2].z, ar[2].w);
      p1.z = pack2bf(ar[3].x, ar[3].y); p1.w = pack2bf(ar[3].z, ar[3].w);
      const int swz = (arow & 7) << 4;
      const int base = arow * 128;
      *(uint4*)((char*)Al + base + ((aseg * 32) ^ swz)) = p0;
      *(uint4*)((char*)Al + base + ((aseg * 32 + 16) ^ swz)) = p1;
    }
    // stage B (bf16): 256 rows x 128 B, 32 groups of 8 rows (1 KiB each)
    {
#pragma unroll
      for (int q = 0; q < 4; ++q) {
        const int grp = q * 8 + w;
        const int row = grp * 8 + brow_in8;
        const char* g = (const char*)Wbf + (size_t)row * 1024 + kt * 128 +
                        bkb_src;
        gload_lds16(g, (char*)Bl + grp * 1024);
      }
    }
    __syncthreads();   // drains vmcnt+lgkm: A and B tiles ready

    // prefetch A regs for chunk kt+1 (flies under the MFMA phase)
    if (kt < 7) {
      const int cs = (kt + 1) * 4 + aseg;
      const int token = tokL[arow * 4 + (cs >> 3)];
      const float* asrc = x + ((size_t)bb * NS + token) * ND + ((cs * 16) & 127);
#pragma unroll
      for (int q = 0; q < 4; ++q) ar[q] = ((const float4*)asrc)[q];
    }

    // compute: 2 kk-steps x 16 MFMA per wave
    const int swz = (lrow & 7) << 4;
#pragma unroll
    for (int kk = 0; kk < 2; ++kk) {
      const int koff = (kk * 64 + lk * 16) ^ swz;
      bf16x8 af[4], bfr[4];
#pragma unroll
      for (int m = 0; m < 4; ++m)
        af[m] = *(const bf16x8*)((const char*)Al +
                                 (wr * 64 + m * 16 + lrow) * 128 + koff);
#pragma unroll
      for (int n = 0; n < 4; ++n)
        bfr[n] = *(const bf16x8*)((const char*)Bl +
                                  (wc * 64 + n * 16 + lrow) * 128 + koff);
#pragma unroll
      for (int m = 0; m < 4; ++m)
#pragma unroll
        for (int n = 0; n < 4; ++n)
          acc[m][n] = __builtin_amdgcn_mfma_f32_16x16x32_bf16(
              af[m], bfr[n], acc[m][n], 0, 0, 0);
    }
    __syncthreads();   // LDS consumed; safe to overwrite next iter
  }

  // --- epilogue: bias + deterministic bernoulli + relu + column partials ---
  float bias_n[4];
#pragma unroll
  for (int n = 0; n < 4; ++n) bias_n[n] = bfc[wc * 64 + n * 16 + lrow];

  const int rowbase = m0 + wr * 64 + lk * 4;
  float csum[4] = {0.f, 0.f, 0.f, 0.f};
#pragma unroll
  for (int n = 0; n < 4; ++n) {
    const unsigned int gcol = (unsigned int)(wc * 64 + n * 16 + lrow);
#pragma unroll
    for (int m = 0; m < 4; ++m) {
#pragma unroll
      for (int reg = 0; reg < 4; ++reg) {
        const unsigned int gm =
            (unsigned int)(bb * NCLUST + rowbase + m * 16 + reg);
        const unsigned int flat = gm * 256u + gcol;
        const bool keep = mask_keep(flat);
        float vv = acc[m][n][reg] + bias_n[n];
        vv = keep ? fmaxf(vv, 0.0f) : 0.0f;
        csum[n] += vv;
      }
    }
  }
  // reduce across lk groups within wave
#pragma unroll
  for (int n = 0; n < 4; ++n) {
    csum[n] += __shfl_xor(csum[n], 16);
    csum[n] += __shfl_xor(csum[n], 32);
  }
  if (l < 16) {
#pragma unroll
    for (int n = 0; n < 4; ++n) red[w][n * 16 + l] = csum[n];
  }
  __syncthreads();
  if (t < HIDN) {
    const int cwc = t >> 6, c = t & 63;
    const float s = red[cwc][c] + red[cwc + 4][c];
    atomicAdd(&xc[bb * HIDN + t], s);
  }
}

// ---------------- kernel 4: mean + memory MLP + output head ----------------
__global__ __launch_bounds__(128) void tail_kernel(
    const float* __restrict__ xc, const float* __restrict__ memory,
    const float* __restrict__ Wmem, const float* __restrict__ bmem,
    const float* __restrict__ Wout, const float* __restrict__ bout,
    float* __restrict__ out) {
  __shared__ __align__(16) float xl[HIDN];
  __shared__ float ul[NMEM];
  const int b = blockIdx.x, t = threadIdx.x;
  xl[t]       = xc[b * HIDN + t] * (1.0f / NCLUST);
  xl[t + 128] = xc[b * HIDN + t + 128] * (1.0f / NCLUST);
  __syncthreads();
  float a = 0.0f;
  const float4* wr2 = (const float4*)(Wmem + (size_t)t * HIDN);
#pragma unroll 4
  for (int q = 0; q < HIDN / 4; ++q) {
    const float4 wv = wr2[q];
    const float4 xv = *(const float4*)&xl[q * 4];
    a = fmaf(wv.x, xv.x, a); a = fmaf(wv.y, xv.y, a);
    a = fmaf(wv.z, xv.z, a); a = fmaf(wv.w, xv.w, a);
  }
  a += bmem[t] + memory[b * NMEM + t];
  a = fmaxf(a, 0.0f);
  ul[t] = a;
  out[NB * NCLS + b * NMEM + t] = a;
  __syncthreads();
  if (t < NCLS) {
    float o = 0.0f;
#pragma unroll 4
    for (int m = 0; m < NMEM; ++m) o = fmaf(ul[m], Wout[t * NMEM + m], o);
    out[b * NCLS + t] = o + bout[t];
  }
}

// ---------------- launcher ----------------
extern "C" void kernel_launch(void* const* d_in, const int* in_sizes, int n_in,
                              void* d_out, int out_size, void* d_ws, size_t ws_size,
                              hipStream_t stream) {
  (void)in_sizes; (void)n_in; (void)out_size; (void)ws_size;
  const float* x    = (const float*)d_in[0];
  const float* mem  = (const float*)d_in[1];
  const float* Wfc  = (const float*)d_in[2];
  const float* bfc  = (const float*)d_in[3];
  const float* Wmem = (const float*)d_in[4];
  const float* bmem = (const float*)d_in[5];
  const float* Wout = (const float*)d_in[6];
  const float* bout = (const float*)d_in[7];
  float* out = (float*)d_out;

  char* ws = (char*)d_ws;
  ull* keys = (ull*)ws;                                               // 2 MiB
  unsigned int* topk = (unsigned int*)(ws + (size_t)NB * NS * 8);     // 512 KiB
  float* xc = (float*)(ws + (size_t)NB * NS * 8 + (size_t)NB * KTOP * 4);
  unsigned short* Wbf = (unsigned short*)(ws + (size_t)NB * NS * 8 +
                                          (size_t)NB * KTOP * 4 +
                                          (size_t)NB * HIDN * 4);     // 256 KiB

  norms_kernel<<<dim3(NORM_BLOCKS + 64), 256, 0, stream>>>(x, keys, xc, Wfc,
                                                           Wbf);
  sortA_kernel<<<dim3(NB * 2), 512, 0, stream>>>(keys);
  sortB_kernel<<<dim3(NB), 512, 0, stream>>>(keys, topk);
  gemm_kernel<<<dim3(256), 512, 0, stream>>>(x, Wbf, bfc, topk, xc);
  tail_kernel<<<dim3(NB), 128, 0, stream>>>(xc, mem, Wmem, bmem, Wout, bout, out);
}

// Round 5
// 269.843 us; speedup vs baseline: 1.5868x; 1.0266x over previous
//
#include <hip/hip_runtime.h>
#include <stdint.h>

#define NB 32
#define NS 8192
#define ND 128
#define KTOP 4096
#define NCLUST 1024
#define CIN 512
#define HIDN 256
#define NMEM 128
#define NCLS 10
#define HALFCNT 4194304u   // (NB*NCLUST*HIDN)/2

typedef unsigned long long ull;
typedef __attribute__((ext_vector_type(8))) short bf16x8;
typedef __attribute__((ext_vector_type(4))) float f32x4;

// ---------------- threefry2x32-20, JAX-exact, key = (0, 1234) ----------------
__device__ __forceinline__ unsigned int rotl32(unsigned int v, int r) {
  return (v << r) | (v >> (32 - r));
}

__device__ __forceinline__ void threefry_block(unsigned int& x0, unsigned int& x1) {
  const unsigned int k0 = 0u;
  const unsigned int k1 = 1234u;
  const unsigned int k2 = 0x1BD11BDAu ^ 0u ^ 1234u;
  x0 += k0; x1 += k1;
#define TF_R(r) { x0 += x1; x1 = rotl32(x1, (r)); x1 ^= x0; }
  TF_R(13) TF_R(15) TF_R(26) TF_R(6)   x0 += k1; x1 += k2 + 1u;
  TF_R(17) TF_R(29) TF_R(16) TF_R(24)  x0 += k2; x1 += k0 + 2u;
  TF_R(13) TF_R(15) TF_R(26) TF_R(6)   x0 += k0; x1 += k1 + 3u;
  TF_R(17) TF_R(29) TF_R(16) TF_R(24)  x0 += k1; x1 += k2 + 4u;
  TF_R(13) TF_R(15) TF_R(26) TF_R(6)   x0 += k2; x1 += k0 + 5u;
#undef TF_R
}

__device__ __forceinline__ unsigned int f2bf(float f) {
  unsigned int u = __float_as_uint(f);
  return (u + 0x7fffu + ((u >> 16) & 1u)) >> 16;
}
__device__ __forceinline__ unsigned int pack2bf(float lo, float hi) {
  return f2bf(lo) | (f2bf(hi) << 16);
}

__device__ __forceinline__ void gload_lds16(const void* g, void* l) {
  __builtin_amdgcn_global_load_lds(
      (const __attribute__((address_space(1))) unsigned int*)g,
      (__attribute__((address_space(3))) unsigned int*)l, 16, 0, 0);
}

__device__ __forceinline__ ull shfl_xor_u64(ull x, int m) {
  unsigned int lo = (unsigned int)x, hi = (unsigned int)(x >> 32);
  lo = (unsigned int)__shfl_xor((int)lo, m);
  hi = (unsigned int)__shfl_xor((int)hi, m);
  return ((ull)hi << 32) | lo;
}

// ------- kernel 1: token norms -> sort keys; zero xc; fused W_fc->bf16 ------
#define NORM_BLOCKS 32768
__global__ __launch_bounds__(256) void norms_kernel(
    const float* __restrict__ x, ull* __restrict__ keys,
    float* __restrict__ xc, const float* __restrict__ Wfc,
    unsigned short* __restrict__ Wbf) {
  const int blk = blockIdx.x;
  if (blk >= NORM_BLOCKS) {
    // W_fc f32 -> bf16, same [256][512] layout
    const int t = (blk - NORM_BLOCKS) * 256 + threadIdx.x;
    const float4* s = (const float4*)(Wfc + (size_t)t * 8);
    const float4 a = s[0], b = s[1];
    uint4 o;
    o.x = pack2bf(a.x, a.y); o.y = pack2bf(a.z, a.w);
    o.z = pack2bf(b.x, b.y); o.w = pack2bf(b.z, b.w);
    *(uint4*)(Wbf + (size_t)t * 8) = o;
    return;
  }
  const int t = blk * 256 + threadIdx.x;
  if (t < NB * HIDN) xc[t] = 0.0f;
  const int token = t >> 5;
  const int l = t & 31;
  const float4 v = ((const float4*)(x + (size_t)token * ND))[l];
  float ss = v.x * v.x + v.y * v.y + v.z * v.z + v.w * v.w;
#pragma unroll
  for (int off = 16; off >= 1; off >>= 1) ss += __shfl_xor(ss, off);
  if (l == 0) {
    const float nrm = sqrtf(ss);
    const unsigned int ub = ~__float_as_uint(nrm);
    keys[token] = ((ull)ub << 32) | (unsigned int)(token & (NS - 1));
  }
}

// ---- kernel 2a: per-half bitonic sort (4096 elems, asc for half 0, desc 1) --
#define CMPEX(J, K, HF)                                                 \
  {                                                                     \
    _Pragma("unroll") for (int r = 0; r < 8; ++r) {                     \
      if ((r & (J)) == 0) {                                             \
        const int i0 = (tid << 3) + r;                                  \
        const bool up2 = (((i0 & (K)) == 0) != (HF));                   \
        const ull lo = v[r], hi = v[r | (J)];                           \
        const ull mn = lo < hi ? lo : hi;                               \
        const ull mx = lo < hi ? hi : lo;                               \
        v[r] = up2 ? mn : mx;                                           \
        v[r | (J)] = up2 ? mx : mn;                                     \
      }                                                                 \
    }                                                                   \
  }

__global__ __launch_bounds__(512) void sortA_kernel(ull* __restrict__ keys) {
  __shared__ ull slds[8 * 512];          // 32 KiB, transposed [r][tid]
  const int b = blockIdx.x >> 1;
  const int half = blockIdx.x & 1;
  const bool hf = (half != 0);
  const int tid = threadIdx.x;
  ull v[8];
  ull* base = keys + (size_t)b * NS + half * 4096;
#pragma unroll
  for (int r = 0; r < 8; ++r) v[r] = base[tid * 8 + r];

  for (int k = 2; k <= 4096; k <<= 1) {
    // cross-wave rounds via LDS (j = 512..2048)
    for (int j = k >> 1; j >= 512; j >>= 1) {
      __syncthreads();
#pragma unroll
      for (int r = 0; r < 8; ++r) slds[r * 512 + tid] = v[r];
      __syncthreads();
      const int ptid = tid ^ (j >> 3);
      const bool up2 = ((((tid << 3) & k) == 0) != hf);
      const bool lower = (((tid << 3) & j) == 0);
      const bool keepmin = (up2 == lower);
#pragma unroll
      for (int r = 0; r < 8; ++r) {
        const ull p = slds[r * 512 + ptid];
        const ull mn = v[r] < p ? v[r] : p;
        const ull mx = v[r] < p ? p : v[r];
        v[r] = keepmin ? mn : mx;
      }
    }
    // intra-wave rounds via shfl (j = 8..256)
    {
      const int jstart = (k >> 1) < 256 ? (k >> 1) : 256;
      for (int j = jstart; j >= 8; j >>= 1) {
        const int lanemask = j >> 3;
        const bool up2 = ((((tid << 3) & k) == 0) != hf);
        const bool lower = (((tid << 3) & j) == 0);
        const bool keepmin = (up2 == lower);
#pragma unroll
        for (int r = 0; r < 8; ++r) {
          const ull p = shfl_xor_u64(v[r], lanemask);
          const ull mn = v[r] < p ? v[r] : p;
          const ull mx = v[r] < p ? p : v[r];
          v[r] = keepmin ? mn : mx;
        }
      }
    }
    // in-register rounds (j = 4,2,1)
    if (k >= 8)      { CMPEX(4, k, hf) CMPEX(2, k, hf) CMPEX(1, k, hf) }
    else if (k == 4) { CMPEX(2, k, hf) CMPEX(1, k, hf) }
    else             { CMPEX(1, k, hf) }
  }

#pragma unroll
  for (int r = 0; r < 8; ++r) base[tid * 8 + r] = v[r];
}

// ---- kernel 2b: merge asc-half + desc-half, keep top 4096 (lower), sorted ---
__global__ __launch_bounds__(512) void sortB_kernel(
    const ull* __restrict__ keys, unsigned int* __restrict__ topk) {
  __shared__ ull slds[8 * 512];          // 32 KiB (lower half only)
  const int b = blockIdx.x;
  const int tid = threadIdx.x;
  ull v[8];
  const ull* base = keys + (size_t)b * NS;
#pragma unroll
  for (int r = 0; r < 8; ++r) v[r] = base[tid * 8 + r];
  // j = 4096 round: partner of i is i+4096 -> pure per-thread min
#pragma unroll
  for (int r = 0; r < 8; ++r) {
    const ull u = base[4096 + tid * 8 + r];
    v[r] = v[r] < u ? v[r] : u;
  }
  // bitonic-merge lower half: j = 2048,1024,512 via LDS
  for (int j = 2048; j >= 512; j >>= 1) {
    __syncthreads();
#pragma unroll
    for (int r = 0; r < 8; ++r) slds[r * 512 + tid] = v[r];
    __syncthreads();
    const int ptid = tid ^ (j >> 3);
    const bool keepmin = (((tid << 3) & j) == 0);
#pragma unroll
    for (int r = 0; r < 8; ++r) {
      const ull p = slds[r * 512 + ptid];
      const ull mn = v[r] < p ? v[r] : p;
      const ull mx = v[r] < p ? p : v[r];
      v[r] = keepmin ? mn : mx;
    }
  }
  // j = 256..8 via shfl
  for (int j = 256; j >= 8; j >>= 1) {
    const int lanemask = j >> 3;
    const bool keepmin = (((tid << 3) & j) == 0);
#pragma unroll
    for (int r = 0; r < 8; ++r) {
      const ull p = shfl_xor_u64(v[r], lanemask);
      const ull mn = v[r] < p ? v[r] : p;
      const ull mx = v[r] < p ? p : v[r];
      v[r] = keepmin ? mn : mx;
    }
  }
  // j = 4,2,1 in registers (ascending merge: up2 always true)
  CMPEX(4, 8192, false) CMPEX(2, 8192, false) CMPEX(1, 8192, false)
#pragma unroll
  for (int r = 0; r < 8; ++r)
    topk[b * KTOP + tid * 8 + r] = (unsigned int)v[r];
}

// ------ kernel 3: gather + bf16 MFMA GEMM + bias + mask + relu + col-sum ----
// TLP restructure: 1024 blocks x 256 threads (4 waves), 4 blocks/CU.
// Tile: 32 rows (16 of batch bb + 16 of batch bb+16) x 256 cols, BK=64.
// Batch-pairing: one threefry call yields mask bits for BOTH batches
// (flat(bb+16) = flat(bb) + HALFCNT); m-frag index selects the batch.
__global__ __launch_bounds__(256, 4) void gemm_kernel(
    const float* __restrict__ x, const unsigned short* __restrict__ Wbf,
    const float* __restrict__ bfc, const unsigned int* __restrict__ topk,
    float* __restrict__ xc) {
  __shared__ __align__(16) unsigned short Al[32 * 64];    // 4 KiB, swizzled
  __shared__ __align__(16) unsigned short Bl[256 * 64];   // 32 KiB, swizzled
  __shared__ int tokL[128];   // [row 0..31][slot 0..3]; row<16: bb, else bb+16

  const int bid = blockIdx.x;            // 1024 = 16 pairs x 64 m-tiles
  const int bb = bid >> 6;               // batch pair (bb, bb+16), bb in [0,16)
  const int m0c = (bid & 63) * 16;       // cluster base within each batch
  const int t = threadIdx.x;
  const int w = t >> 6, l = t & 63;      // wave w owns cols [w*64, w*64+64)
  const int lrow = l & 15, lk = l >> 4;

  if (t < 128) {
    const int r = t >> 2, s = t & 3;     // r in [0,32): row, s: slot
    const int batch = (r < 16) ? bb : bb + 16;
    tokL[t] = (int)topk[batch * KTOP + (m0c + (r & 15)) * 4 + s];
  }
  __syncthreads();

  f32x4 acc[2][4];
#pragma unroll
  for (int m = 0; m < 2; ++m)
#pragma unroll
    for (int n = 0; n < 4; ++n) acc[m][n] = (f32x4)0.f;

  // --- A-stage mapping: arow = t>>3 (0..31), kq = t&7 (8 floats = 32 B) ---
  const int arow = t >> 3, kq = t & 7;
  const int abatch = (arow < 16) ? bb : bb + 16;
  float4 ar[2];
  {
    const int cs = kq;                   // kt=0
    const int token = tokL[arow * 4 + (cs >> 4)];
    const float* asrc =
        x + ((size_t)abatch * NS + token) * ND + (cs & 15) * 8;
    ar[0] = ((const float4*)asrc)[0];
    ar[1] = ((const float4*)asrc)[1];
  }

  // per-lane source swizzle for B staging (linear LDS dest, swizzled source)
  const int brow_in8 = l >> 3;
  const int bkb_src = ((l & 7) * 16) ^ (brow_in8 << 4);

  for (int kt = 0; kt < 8; ++kt) {
    // write A regs (chunk kt) to swizzled LDS: 1 uint4 per thread
    {
      uint4 p0;
      p0.x = pack2bf(ar[0].x, ar[0].y); p0.y = pack2bf(ar[0].z, ar[0].w);
      p0.z = pack2bf(ar[1].x, ar[1].y); p0.w = pack2bf(ar[1].z, ar[1].w);
      const int swz = (arow & 7) << 4;
      *(uint4*)((char*)Al + arow * 128 + ((kq * 16) ^ swz)) = p0;
    }
    // stage B (bf16): 256 rows x 128 B = 32 groups of 1 KiB; wave w: 8 groups
    {
#pragma unroll
      for (int q = 0; q < 8; ++q) {
        const int grp = w * 8 + q;
        const int row = grp * 8 + brow_in8;
        const char* g = (const char*)Wbf + (size_t)row * 1024 + kt * 128 +
                        bkb_src;
        gload_lds16(g, (char*)Bl + grp * 1024);
      }
    }
    __syncthreads();   // A + B tiles ready

    // prefetch A regs for chunk kt+1 (flies under the MFMA phase)
    if (kt < 7) {
      const int cs = (kt + 1) * 8 + kq;
      const int token = tokL[arow * 4 + (cs >> 4)];
      const float* asrc =
          x + ((size_t)abatch * NS + token) * ND + (cs & 15) * 8;
      ar[0] = ((const float4*)asrc)[0];
      ar[1] = ((const float4*)asrc)[1];
    }

    // compute: 2 kk-steps x 8 MFMA per wave
    const int swz = (lrow & 7) << 4;
#pragma unroll
    for (int kk = 0; kk < 2; ++kk) {
      const int koff = (kk * 64 + lk * 16) ^ swz;
      bf16x8 af[2], bfr[4];
#pragma unroll
      for (int m = 0; m < 2; ++m)
        af[m] = *(const bf16x8*)((const char*)Al +
                                 (m * 16 + lrow) * 128 + koff);
#pragma unroll
      for (int n = 0; n < 4; ++n)
        bfr[n] = *(const bf16x8*)((const char*)Bl +
                                  (w * 64 + n * 16 + lrow) * 128 + koff);
#pragma unroll
      for (int m = 0; m < 2; ++m)
#pragma unroll
        for (int n = 0; n < 4; ++n)
          acc[m][n] = __builtin_amdgcn_mfma_f32_16x16x32_bf16(
              af[m], bfr[n], acc[m][n], 0, 0, 0);
    }
    __syncthreads();   // LDS consumed; safe to overwrite next iter
  }

  // --- epilogue: bias + paired bernoulli + relu + column partials ---
  float bias_n[4];
#pragma unroll
  for (int n = 0; n < 4; ++n) bias_n[n] = bfc[w * 64 + n * 16 + lrow];

  float csum[2][4] = {{0.f, 0.f, 0.f, 0.f}, {0.f, 0.f, 0.f, 0.f}};
#pragma unroll
  for (int n = 0; n < 4; ++n) {
    const unsigned int gcol = (unsigned int)(w * 64 + n * 16 + lrow);
#pragma unroll
    for (int reg = 0; reg < 4; ++reg) {
      const unsigned int crow = (unsigned int)(m0c + lk * 4 + reg);
      const unsigned int flat = ((unsigned int)bb * 1024u + crow) * 256u + gcol;
      unsigned int a = flat, b2 = flat + HALFCNT;
      threefry_block(a, b2);
      const bool keep0 = (a & 0x80000000u) == 0u;
      const bool keep1 = (b2 & 0x80000000u) == 0u;
      float v0 = acc[0][n][reg] + bias_n[n];
      float v1 = acc[1][n][reg] + bias_n[n];
      v0 = keep0 ? fmaxf(v0, 0.0f) : 0.0f;
      v1 = keep1 ? fmaxf(v1, 0.0f) : 0.0f;
      csum[0][n] += v0;
      csum[1][n] += v1;
    }
  }
  // reduce across lk groups within wave; waves own disjoint cols
#pragma unroll
  for (int p = 0; p < 2; ++p)
#pragma unroll
    for (int n = 0; n < 4; ++n) {
      csum[p][n] += __shfl_xor(csum[p][n], 16);
      csum[p][n] += __shfl_xor(csum[p][n], 32);
    }
  if (l < 16) {
#pragma unroll
    for (int n = 0; n < 4; ++n) {
      atomicAdd(&xc[bb * HIDN + w * 64 + n * 16 + l], csum[0][n]);
      atomicAdd(&xc[(bb + 16) * HIDN + w * 64 + n * 16 + l], csum[1][n]);
    }
  }
}

// ---------------- kernel 4: mean + memory MLP + output head ----------------
__global__ __launch_bounds__(128) void tail_kernel(
    const float* __restrict__ xc, const float* __restrict__ memory,
    const float* __restrict__ Wmem, const float* __restrict__ bmem,
    const float* __restrict__ Wout, const float* __restrict__ bout,
    float* __restrict__ out) {
  __shared__ __align__(16) float xl[HIDN];
  __shared__ float ul[NMEM];
  const int b = blockIdx.x, t = threadIdx.x;
  xl[t]       = xc[b * HIDN + t] * (1.0f / NCLUST);
  xl[t + 128] = xc[b * HIDN + t + 128] * (1.0f / NCLUST);
  __syncthreads();
  float a = 0.0f;
  const float4* wr2 = (const float4*)(Wmem + (size_t)t * HIDN);
#pragma unroll 4
  for (int q = 0; q < HIDN / 4; ++q) {
    const float4 wv = wr2[q];
    const float4 xv = *(const float4*)&xl[q * 4];
    a = fmaf(wv.x, xv.x, a); a = fmaf(wv.y, xv.y, a);
    a = fmaf(wv.z, xv.z, a); a = fmaf(wv.w, xv.w, a);
  }
  a += bmem[t] + memory[b * NMEM + t];
  a = fmaxf(a, 0.0f);
  ul[t] = a;
  out[NB * NCLS + b * NMEM + t] = a;
  __syncthreads();
  if (t < NCLS) {
    float o = 0.0f;
#pragma unroll 4
    for (int m = 0; m < NMEM; ++m) o = fmaf(ul[m], Wout[t * NMEM + m], o);
    out[b * NCLS + t] = o + bout[t];
  }
}

// ---------------- launcher ----------------
extern "C" void kernel_launch(void* const* d_in, const int* in_sizes, int n_in,
                              void* d_out, int out_size, void* d_ws, size_t ws_size,
                              hipStream_t stream) {
  (void)in_sizes; (void)n_in; (void)out_size; (void)ws_size;
  const float* x    = (const float*)d_in[0];
  const float* mem  = (const float*)d_in[1];
  const float* Wfc  = (const float*)d_in[2];
  const float* bfc  = (const float*)d_in[3];
  const float* Wmem = (const float*)d_in[4];
  const float* bmem = (const float*)d_in[5];
  const float* Wout = (const float*)d_in[6];
  const float* bout = (const float*)d_in[7];
  float* out = (float*)d_out;

  char* ws = (char*)d_ws;
  ull* keys = (ull*)ws;                                               // 2 MiB
  unsigned int* topk = (unsigned int*)(ws + (size_t)NB * NS * 8);     // 512 KiB
  float* xc = (float*)(ws + (size_t)NB * NS * 8 + (size_t)NB * KTOP * 4);
  unsigned short* Wbf = (unsigned short*)(ws + (size_t)NB * NS * 8 +
                                          (size_t)NB * KTOP * 4 +
                                          (size_t)NB * HIDN * 4);     // 256 KiB

  norms_kernel<<<dim3(NORM_BLOCKS + 64), 256, 0, stream>>>(x, keys, xc, Wfc,
                                                           Wbf);
  sortA_kernel<<<dim3(NB * 2), 512, 0, stream>>>(keys);
  sortB_kernel<<<dim3(NB), 512, 0, stream>>>(keys, topk);
  gemm_kernel<<<dim3(1024), 256, 0, stream>>>(x, Wbf, bfc, topk, xc);
  tail_kernel<<<dim3(NB), 128, 0, stream>>>(xc, mem, Wmem, bmem, Wout, bout, out);
}